// Round 16
// baseline (430.952 us; speedup 1.0000x reference)
//
#include <hip/hip_runtime.h>

// ---------------------------------------------------------------------------
// DepTreeLSTM on MI355X — round 16: tail pair-fusion.
//   fused_kernel (R15, unchanged): {leaf, lvl1} per 2 trees, 2048 blocks.
//   pair_kernel<PT,CAL,OFFA,OFFB,WRC>: {lvlA, lvlB=A+1} per PT trees.
//     Phase A: gather child h/c from HBM (hout/cbuf), GEMM MT2 K512 NT5,
//              h->hout + LDS stash; c->stash ONLY (dead cbuf write removed).
//     Phase B: child h/c from stash, GEMM MT1, h->hout, c->cbuf iff WRC.
//   pair1 = {lvl2,lvl3}: PT=4, 1024 blocks, WRC=1 (lvl3 c feeds pair2).
//   pair2 = {lvl4,lvl5}: PT=16, 256 blocks, WRC=0 (all c dead).
// LDS pair: A 32K + hstash 8K + cstash 16K = 56KB -> 2 blocks/CU.
// ws: BTf bf16 fragment-packed at 0; c-state f32 [N][128] at 1MB.
// ---------------------------------------------------------------------------

typedef float f32x4 __attribute__((ext_vector_type(4)));
typedef __bf16 bf16x8 __attribute__((ext_vector_type(8)));
typedef unsigned short u16x8 __attribute__((ext_vector_type(8)));

__device__ __forceinline__ unsigned short f2bf(float x) {
  union { __bf16 b; unsigned short u; } cv;
  cv.b = (__bf16)x;
  return cv.u;
}
__device__ __forceinline__ float bf2f(unsigned short u) {
  return __uint_as_float(((unsigned int)u) << 16);
}
__device__ __forceinline__ float sigf(float x) { return 1.f / (1.f + __expf(-x)); }
__device__ __forceinline__ float tanhfast(float x) {
  return 1.f - 2.f / (__expf(2.f * x) + 1.f);
}

// Pack B in fragment order: BTf[((tile*16 + ks)*64 + lane)*8 + j]
// lane = kq*16 + cl, col = tile*16+cl, k = ks*32 + kq*8 + j  (K=512).
// col<384: W_iou/U_iou; col>=384: W_f (dup f0/f1) / U_f_w.
__global__ void prep_kernel(const float* __restrict__ Wi, const float* __restrict__ Ui,
                            const float* __restrict__ Wf, const float* __restrict__ Uf,
                            unsigned short* __restrict__ BTf) {
  int idx = blockIdx.x * 256 + threadIdx.x;
  int j = idx & 7;
  int lane = (idx >> 3) & 63;
  int ks = (idx >> 9) & 15;
  int tile = idx >> 13;
  int cl = lane & 15, kq = lane >> 4;
  int col = tile * 16 + cl;
  int k = ks * 32 + kq * 8 + j;
  float v;
  if (k < 256) {
    v = (col < 384) ? Wi[k * 384 + col] : Wf[k * 128 + ((col - 384) & 127)];
  } else {
    int kk = k & 255;
    v = (col < 384) ? Ui[kk * 384 + col] : Uf[kk * 256 + (col - 384)];
  }
  BTf[idx] = f2bf(v);
}

// A-LDS fragment-order address (elements): ((mt*NKS + ks)*64 + kq*16 + r)*8 + j
template <int NKS>
__device__ __forceinline__ int a_addr(int rblk, int k) {
  int mt = rblk >> 4, r = rblk & 15;
  int ks = k >> 5, kq = (k >> 3) & 3, j = k & 7;
  return (((mt * NKS + ks) * 64 + (kq << 4) + r) << 3) + j;
}

// ======================= fused leaf + lvl1 kernel (R15) ====================
__global__ __launch_bounds__(512, 4) void fused_kernel(
    const float* __restrict__ emb, const float* __restrict__ cmask,
    const int* __restrict__ ctype,
    const unsigned short* __restrict__ BTf,
    const float* __restrict__ b_iou, const float* __restrict__ ufb,
    const float* __restrict__ bf_,
    float* __restrict__ hout, float* __restrict__ cbuf) {
  __shared__ unsigned short Alds[16384];
  __shared__ unsigned short hstash[8192];
  __shared__ float cstash[8192];

  const int tid = threadIdx.x;
  const int lane = tid & 63;
  const int w = tid >> 6;
  const int cl = lane & 15;
  const int rb = (lane >> 4) << 2;
  const int hcol = w * 16 + cl;
  const int g0 = blockIdx.x * 126;

  const unsigned short* Bw = BTf + (size_t)w * 8192 + lane * 8;

#pragma unroll
  for (int c = 0; c < 4; ++c) {
    const int ks_e = tid >> 6;
    const int lq = tid & 63;
    const int k0 = ks_e * 32 + (lq >> 4) * 8;
    const int rblk = c * 16 + (lq & 15);
    const int g = g0 + (rblk >> 5) * 63 + (rblk & 31);
    const float4 v0 = *(const float4*)&emb[(size_t)g * 256 + k0];
    const float4 v1 = *(const float4*)&emb[(size_t)g * 256 + k0 + 4];
    ushort4 p0, p1;
    p0.x = f2bf(v0.x); p0.y = f2bf(v0.y); p0.z = f2bf(v0.z); p0.w = f2bf(v0.w);
    p1.x = f2bf(v1.x); p1.y = f2bf(v1.y); p1.z = f2bf(v1.z); p1.w = f2bf(v1.w);
    unsigned short* dst = &Alds[((c * 8 + ks_e) * 64 + lq) * 8];
    *(ushort4*)dst = p0;
    *(ushort4*)(dst + 4) = p1;
  }
  __syncthreads();

  {
    f32x4 acc[4][3];
#pragma unroll
    for (int mt = 0; mt < 4; ++mt)
#pragma unroll
      for (int t = 0; t < 3; ++t) acc[mt][t] = (f32x4){0.f, 0.f, 0.f, 0.f};
    bf16x8 bA[3], bB[3];
#pragma unroll
    for (int t = 0; t < 3; ++t) bA[t] = *(const bf16x8*)&Bw[(size_t)t * 65536];
    auto step0 = [&](bf16x8(&cur)[3], bf16x8(&nxt)[3], int ks) {
      if (ks + 1 < 8) {
#pragma unroll
        for (int t = 0; t < 3; ++t)
          nxt[t] = *(const bf16x8*)&Bw[(size_t)t * 65536 + (ks + 1) * 512];
      }
      __builtin_amdgcn_s_setprio(1);
#pragma unroll
      for (int mt = 0; mt < 4; ++mt) {
        const bf16x8 a = *(const bf16x8*)&Alds[((mt * 8 + ks) * 64 + lane) << 3];
#pragma unroll
        for (int t = 0; t < 3; ++t)
          acc[mt][t] = __builtin_amdgcn_mfma_f32_16x16x32_bf16(a, cur[t], acc[mt][t], 0, 0, 0);
      }
      __builtin_amdgcn_s_setprio(0);
    };
#pragma unroll
    for (int ks2 = 0; ks2 < 4; ++ks2) {
      step0(bA, bB, 2 * ks2);
      step0(bB, bA, 2 * ks2 + 1);
    }
    const float bi = b_iou[hcol], bo = b_iou[128 + hcol], bu = b_iou[256 + hcol];
#pragma unroll
    for (int mt = 0; mt < 4; ++mt) {
#pragma unroll
      for (int r = 0; r < 4; ++r) {
        const int row = (mt << 4) + rb + r;
        const int g = g0 + (row >> 5) * 63 + (row & 31);
        const float cn = sigf(acc[mt][0][r] + bi) * tanhfast(acc[mt][2][r] + bu);
        const float hn = sigf(acc[mt][1][r] + bo) * tanhfast(cn);
        hout[(size_t)g * 128 + hcol] = hn;
        hstash[row * 128 + hcol] = f2bf(hn);
        cstash[row * 128 + hcol] = cn;
      }
    }
  }
  __syncthreads();

#pragma unroll
  for (int c = 0; c < 2; ++c) {
    const int ks_e = tid >> 6;
    const int lq = tid & 63;
    const int k0 = ks_e * 32 + (lq >> 4) * 8;
    const int rblk = c * 16 + (lq & 15);
    const int g = g0 + (rblk >> 4) * 63 + 32 + (rblk & 15);
    const float4 v0 = *(const float4*)&emb[(size_t)g * 256 + k0];
    const float4 v1 = *(const float4*)&emb[(size_t)g * 256 + k0 + 4];
    ushort4 p0, p1;
    p0.x = f2bf(v0.x); p0.y = f2bf(v0.y); p0.z = f2bf(v0.z); p0.w = f2bf(v0.w);
    p1.x = f2bf(v1.x); p1.y = f2bf(v1.y); p1.z = f2bf(v1.z); p1.w = f2bf(v1.w);
    unsigned short* dst = &Alds[((c * 16 + ks_e) * 64 + lq) * 8];
    *(ushort4*)dst = p0;
    *(ushort4*)(dst + 4) = p1;
  }
  {
    const int rblk = tid >> 4, q = tid & 15;
    const int i = rblk >> 4, j = rblk & 15;
    const int gp = g0 + i * 63 + 32 + j;
    const int ch0 = i * 32 + 2 * j, ch1 = ch0 + 1;
    const int ty0 = ctype[2 * gp], ty1 = ctype[2 * gp + 1];
    const float c0 = cmask[2 * gp], c1 = cmask[2 * gp + 1];
    const float w00 = (ty0 == 0) ? c0 : 0.f, w01 = (ty1 == 0) ? c1 : 0.f;
    const float w10 = (ty0 == 1) ? c0 : 0.f, w11 = (ty1 == 1) ? c1 : 0.f;
    const int jc = q * 8;
    const u16x8 va = *(const u16x8*)&hstash[ch0 * 128 + jc];
    const u16x8 vb = *(const u16x8*)&hstash[ch1 * 128 + jc];
    u16x8 o0, o1;
#pragma unroll
    for (int e = 0; e < 8; ++e) {
      const float fa = bf2f(va[e]), fb = bf2f(vb[e]);
      o0[e] = f2bf(w00 * fa + w01 * fb);
      o1[e] = f2bf(w10 * fa + w11 * fb);
    }
    *(u16x8*)&Alds[a_addr<16>(rblk, 256 + jc)] = o0;
    *(u16x8*)&Alds[a_addr<16>(rblk, 384 + jc)] = o1;
  }
  __syncthreads();

  {
    f32x4 acc[2][5];
#pragma unroll
    for (int mt = 0; mt < 2; ++mt)
#pragma unroll
      for (int t = 0; t < 5; ++t) acc[mt][t] = (f32x4){0.f, 0.f, 0.f, 0.f};
    bf16x8 bA[5], bB[5];
#pragma unroll
    for (int t = 0; t < 5; ++t) bA[t] = *(const bf16x8*)&Bw[(size_t)t * 65536];
    auto step1 = [&](bf16x8(&cur)[5], bf16x8(&nxt)[5], int ks) {
      if (ks + 1 < 16) {
#pragma unroll
        for (int t = 0; t < 5; ++t)
          nxt[t] = *(const bf16x8*)&Bw[(size_t)t * 65536 + (ks + 1) * 512];
      }
      __builtin_amdgcn_s_setprio(1);
#pragma unroll
      for (int mt = 0; mt < 2; ++mt) {
        const bf16x8 a = *(const bf16x8*)&Alds[((mt * 16 + ks) * 64 + lane) << 3];
#pragma unroll
        for (int t = 0; t < 5; ++t)
          acc[mt][t] = __builtin_amdgcn_mfma_f32_16x16x32_bf16(a, cur[t], acc[mt][t], 0, 0, 0);
      }
      __builtin_amdgcn_s_setprio(0);
    };
#pragma unroll
    for (int ks2 = 0; ks2 < 8; ++ks2) {
      step1(bA, bB, 2 * ks2);
      step1(bB, bA, 2 * ks2 + 1);
    }
    const float bi = b_iou[hcol], bo = b_iou[128 + hcol], bu = b_iou[256 + hcol];
    const float f0b = ufb[hcol], f1b = ufb[128 + hcol], bfv = bf_[hcol];
#pragma unroll
    for (int mt = 0; mt < 2; ++mt) {
#pragma unroll
      for (int r = 0; r < 4; ++r) {
        const int row = (mt << 4) + rb + r;
        const int i = row >> 4, j = row & 15;
        const int g = g0 + i * 63 + 32 + j;
        const int ch0 = i * 32 + 2 * j, ch1 = ch0 + 1;
        const int ty0 = ctype[2 * g], ty1 = ctype[2 * g + 1];
        const float c0v = cmask[2 * g], c1v = cmask[2 * g + 1];
        const float iv = acc[mt][0][r] + bi;
        const float ov = acc[mt][1][r] + bo;
        const float uv = acc[mt][2][r] + bu;
        const float f0 = acc[mt][3][r] + f0b;
        const float f1 = acc[mt][4][r] + f1b;
        const float fa = (ty0 == 0) ? f0 : f1;
        const float fb = (ty1 == 0) ? f0 : f1;
        const float ft0 = sigf(fa + bfv);
        const float ft1 = sigf(fb + bfv);
        const float ccell = ft0 * cstash[ch0 * 128 + hcol] * c0v +
                            ft1 * cstash[ch1 * 128 + hcol] * c1v;
        const float cn = sigf(iv) * tanhfast(uv) + ccell;
        const float hn = sigf(ov) * tanhfast(cn);
        cbuf[(size_t)g * 128 + hcol] = cn;   // read by pair1 phase A
        hout[(size_t)g * 128 + hcol] = hn;
      }
    }
  }
}

// ======================= pair kernel: {lvlA, lvlA+1} =======================
// PT trees/block. Level A: CA=2^CAL nodes/tree (RA=PT*CA=32 rows, MT2).
// Level B: CB=CA/2 (RB=16 rows, MT1). WRC: write level-B c to cbuf.
template <int PT, int CAL, int OFFA, int OFFB, bool WRC>
__global__ __launch_bounds__(512, 4) void pair_kernel(
    const float* __restrict__ emb, const float* __restrict__ cmask,
    const int* __restrict__ cidx, const int* __restrict__ ctype,
    const unsigned short* __restrict__ BTf,
    const float* __restrict__ b_iou, const float* __restrict__ ufb,
    const float* __restrict__ bf_,
    float* __restrict__ hout, float* __restrict__ cbuf) {
  constexpr int CA = 1 << CAL;
  constexpr int RA = PT * CA;          // 32
  constexpr int RB = RA / 2;           // 16
  static_assert(RA == 32 && RB == 16, "pair geometry");
  __shared__ unsigned short Alds[RA * 512];    // 32 KB
  __shared__ unsigned short hstash[RA * 128];  // 8 KB
  __shared__ float cstash[RA * 128];           // 16 KB

  const int tid = threadIdx.x;
  const int lane = tid & 63;
  const int w = tid >> 6;
  const int cl = lane & 15;
  const int rb = (lane >> 4) << 2;
  const int hcol = w * 16 + cl;
  const int t0 = blockIdx.x * PT;      // first tree

  const unsigned short* Bw = BTf + (size_t)w * 8192 + lane * 8;
  const float bi = b_iou[hcol], bo = b_iou[128 + hcol], bu = b_iou[256 + hcol];
  const float f0b = ufb[hcol], f1b = ufb[128 + hcol], bfv = bf_[hcol];

  // ======== Phase A (level A): 32 rows, MT2, K512 ========
  // emb stage: RA*32 = 1024 items, 2 iters
#pragma unroll
  for (int it = 0; it < 2; ++it) {
    const int f = it * 512 + tid;
    const int rblk = f >> 5, sub = f & 31;
    const int i = rblk >> CAL, j = rblk & (CA - 1);
    const int g = (t0 + i) * 63 + OFFA + j;
    const int k0 = sub * 8;
    const float4 v0 = *(const float4*)&emb[(size_t)g * 256 + k0];
    const float4 v1 = *(const float4*)&emb[(size_t)g * 256 + k0 + 4];
    ushort4 p0, p1;
    p0.x = f2bf(v0.x); p0.y = f2bf(v0.y); p0.z = f2bf(v0.z); p0.w = f2bf(v0.w);
    p1.x = f2bf(v1.x); p1.y = f2bf(v1.y); p1.z = f2bf(v1.z); p1.w = f2bf(v1.w);
    unsigned short* dst = &Alds[a_addr<16>(rblk, k0)];
    *(ushort4*)dst = p0;
    *(ushort4*)(dst + 4) = p1;
  }
  // ht gather from HBM hout: 16 thr/row, 8 f32 cols each
  {
    const int rblk = tid >> 4, q = tid & 15;
    const int i = rblk >> CAL, j = rblk & (CA - 1);
    const int g = (t0 + i) * 63 + OFFA + j;
    const int ch0 = cidx[2 * g], ch1 = cidx[2 * g + 1];
    const int ty0 = ctype[2 * g], ty1 = ctype[2 * g + 1];
    const float c0 = cmask[2 * g], c1 = cmask[2 * g + 1];
    const float w00 = (ty0 == 0) ? c0 : 0.f, w01 = (ty1 == 0) ? c1 : 0.f;
    const float w10 = (ty0 == 1) ? c0 : 0.f, w11 = (ty1 == 1) ? c1 : 0.f;
    const int jv = q * 8;
#pragma unroll
    for (int jj = 0; jj < 2; ++jj) {
      const int jc = jv + jj * 4;
      float4 a = *(const float4*)&hout[(size_t)ch0 * 128 + jc];
      float4 b = *(const float4*)&hout[(size_t)ch1 * 128 + jc];
      ushort4 p0, p1;
      p0.x = f2bf(w00 * a.x + w01 * b.x);
      p0.y = f2bf(w00 * a.y + w01 * b.y);
      p0.z = f2bf(w00 * a.z + w01 * b.z);
      p0.w = f2bf(w00 * a.w + w01 * b.w);
      p1.x = f2bf(w10 * a.x + w11 * b.x);
      p1.y = f2bf(w10 * a.y + w11 * b.y);
      p1.z = f2bf(w10 * a.z + w11 * b.z);
      p1.w = f2bf(w10 * a.w + w11 * b.w);
      *(ushort4*)&Alds[a_addr<16>(rblk, 256 + jc)] = p0;
      *(ushort4*)&Alds[a_addr<16>(rblk, 384 + jc)] = p1;
    }
  }
  __syncthreads();

  {
    f32x4 acc[2][5];
#pragma unroll
    for (int mt = 0; mt < 2; ++mt)
#pragma unroll
      for (int t = 0; t < 5; ++t) acc[mt][t] = (f32x4){0.f, 0.f, 0.f, 0.f};
    bf16x8 bA[5], bB[5];
#pragma unroll
    for (int t = 0; t < 5; ++t) bA[t] = *(const bf16x8*)&Bw[(size_t)t * 65536];
    auto stepA = [&](bf16x8(&cur)[5], bf16x8(&nxt)[5], int ks) {
      if (ks + 1 < 16) {
#pragma unroll
        for (int t = 0; t < 5; ++t)
          nxt[t] = *(const bf16x8*)&Bw[(size_t)t * 65536 + (ks + 1) * 512];
      }
      __builtin_amdgcn_s_setprio(1);
#pragma unroll
      for (int mt = 0; mt < 2; ++mt) {
        const bf16x8 a = *(const bf16x8*)&Alds[((mt * 16 + ks) * 64 + lane) << 3];
#pragma unroll
        for (int t = 0; t < 5; ++t)
          acc[mt][t] = __builtin_amdgcn_mfma_f32_16x16x32_bf16(a, cur[t], acc[mt][t], 0, 0, 0);
      }
      __builtin_amdgcn_s_setprio(0);
    };
#pragma unroll
    for (int ks2 = 0; ks2 < 8; ++ks2) {
      stepA(bA, bB, 2 * ks2);
      stepA(bB, bA, 2 * ks2 + 1);
    }
    // epilogue A: child c from HBM cbuf; h->hout+stash, c->stash ONLY
#pragma unroll
    for (int mt = 0; mt < 2; ++mt) {
#pragma unroll
      for (int r = 0; r < 4; ++r) {
        const int row = (mt << 4) + rb + r;
        const int i = row >> CAL, j = row & (CA - 1);
        const int g = (t0 + i) * 63 + OFFA + j;
        const int ch0 = cidx[2 * g], ch1 = cidx[2 * g + 1];
        const int ty0 = ctype[2 * g], ty1 = ctype[2 * g + 1];
        const float c0v = cmask[2 * g], c1v = cmask[2 * g + 1];
        const float iv = acc[mt][0][r] + bi;
        const float ov = acc[mt][1][r] + bo;
        const float uv = acc[mt][2][r] + bu;
        const float f0 = acc[mt][3][r] + f0b;
        const float f1 = acc[mt][4][r] + f1b;
        const float fa = (ty0 == 0) ? f0 : f1;
        const float fb = (ty1 == 0) ? f0 : f1;
        const float ft0 = sigf(fa + bfv);
        const float ft1 = sigf(fb + bfv);
        const float ccell = ft0 * cbuf[(size_t)ch0 * 128 + hcol] * c0v +
                            ft1 * cbuf[(size_t)ch1 * 128 + hcol] * c1v;
        const float cn = sigf(iv) * tanhfast(uv) + ccell;
        const float hn = sigf(ov) * tanhfast(cn);
        hout[(size_t)g * 128 + hcol] = hn;
        hstash[row * 128 + hcol] = f2bf(hn);
        cstash[row * 128 + hcol] = cn;
      }
    }
  }
  __syncthreads();

  // ======== Phase B (level A+1): 16 rows, MT1, K512 ========
  {
    const int f = tid;                 // RB*32 = 512 items exactly
    const int rblk = f >> 5, sub = f & 31;
    const int iB = rblk >> (CAL - 1), jB = rblk & ((CA / 2) - 1);
    const int g = (t0 + iB) * 63 + OFFB + jB;
    const int k0 = sub * 8;
    const float4 v0 = *(const float4*)&emb[(size_t)g * 256 + k0];
    const float4 v1 = *(const float4*)&emb[(size_t)g * 256 + k0 + 4];
    ushort4 p0, p1;
    p0.x = f2bf(v0.x); p0.y = f2bf(v0.y); p0.z = f2bf(v0.z); p0.w = f2bf(v0.w);
    p1.x = f2bf(v1.x); p1.y = f2bf(v1.y); p1.z = f2bf(v1.z); p1.w = f2bf(v1.w);
    unsigned short* dst = &Alds[a_addr<16>(rblk, k0)];
    *(ushort4*)dst = p0;
    *(ushort4*)(dst + 4) = p1;
  }
  if (tid < RB * 16) {   // ht gather from stash
    const int rblk = tid >> 4, q = tid & 15;
    const int iB = rblk >> (CAL - 1), jB = rblk & ((CA / 2) - 1);
    const int g = (t0 + iB) * 63 + OFFB + jB;
    const int chb = iB * CA + 2 * jB;
    const int ty0 = ctype[2 * g], ty1 = ctype[2 * g + 1];
    const float c0 = cmask[2 * g], c1 = cmask[2 * g + 1];
    const float w00 = (ty0 == 0) ? c0 : 0.f, w01 = (ty1 == 0) ? c1 : 0.f;
    const float w10 = (ty0 == 1) ? c0 : 0.f, w11 = (ty1 == 1) ? c1 : 0.f;
    const int jc = q * 8;
    const u16x8 va = *(const u16x8*)&hstash[chb * 128 + jc];
    const u16x8 vb = *(const u16x8*)&hstash[(chb + 1) * 128 + jc];
    u16x8 o0, o1;
#pragma unroll
    for (int e = 0; e < 8; ++e) {
      const float fa = bf2f(va[e]), fb = bf2f(vb[e]);
      o0[e] = f2bf(w00 * fa + w01 * fb);
      o1[e] = f2bf(w10 * fa + w11 * fb);
    }
    *(u16x8*)&Alds[a_addr<16>(rblk, 256 + jc)] = o0;
    *(u16x8*)&Alds[a_addr<16>(rblk, 384 + jc)] = o1;
  }
  __syncthreads();

  {
    f32x4 acc[1][5];
#pragma unroll
    for (int t = 0; t < 5; ++t) acc[0][t] = (f32x4){0.f, 0.f, 0.f, 0.f};
    bf16x8 bA[5], bB[5];
#pragma unroll
    for (int t = 0; t < 5; ++t) bA[t] = *(const bf16x8*)&Bw[(size_t)t * 65536];
    auto stepB = [&](bf16x8(&cur)[5], bf16x8(&nxt)[5], int ks) {
      if (ks + 1 < 16) {
#pragma unroll
        for (int t = 0; t < 5; ++t)
          nxt[t] = *(const bf16x8*)&Bw[(size_t)t * 65536 + (ks + 1) * 512];
      }
      __builtin_amdgcn_s_setprio(1);
      const bf16x8 a = *(const bf16x8*)&Alds[((ks)*64 + lane) << 3];
#pragma unroll
      for (int t = 0; t < 5; ++t)
        acc[0][t] = __builtin_amdgcn_mfma_f32_16x16x32_bf16(a, cur[t], acc[0][t], 0, 0, 0);
      __builtin_amdgcn_s_setprio(0);
    };
#pragma unroll
    for (int ks2 = 0; ks2 < 8; ++ks2) {
      stepB(bA, bB, 2 * ks2);
      stepB(bB, bA, 2 * ks2 + 1);
    }
#pragma unroll
    for (int r = 0; r < 4; ++r) {
      const int row = rb + r;
      const int iB = row >> (CAL - 1), jB = row & ((CA / 2) - 1);
      const int g = (t0 + iB) * 63 + OFFB + jB;
      const int chb = iB * CA + 2 * jB;
      const int ty0 = ctype[2 * g], ty1 = ctype[2 * g + 1];
      const float c0v = cmask[2 * g], c1v = cmask[2 * g + 1];
      const float iv = acc[0][0][r] + bi;
      const float ov = acc[0][1][r] + bo;
      const float uv = acc[0][2][r] + bu;
      const float f0 = acc[0][3][r] + f0b;
      const float f1 = acc[0][4][r] + f1b;
      const float fa = (ty0 == 0) ? f0 : f1;
      const float fb = (ty1 == 0) ? f0 : f1;
      const float ft0 = sigf(fa + bfv);
      const float ft1 = sigf(fb + bfv);
      const float ccell = ft0 * cstash[chb * 128 + hcol] * c0v +
                          ft1 * cstash[(chb + 1) * 128 + hcol] * c1v;
      const float cn = sigf(iv) * tanhfast(uv) + ccell;
      const float hn = sigf(ov) * tanhfast(cn);
      hout[(size_t)g * 128 + hcol] = hn;
      if (WRC) cbuf[(size_t)g * 128 + hcol] = cn;
    }
  }
}

extern "C" void kernel_launch(void* const* d_in, const int* in_sizes, int n_in,
                              void* d_out, int out_size, void* d_ws, size_t ws_size,
                              hipStream_t stream) {
  (void)in_sizes; (void)n_in; (void)out_size; (void)ws_size;
  const float* emb   = (const float*)d_in[0];
  const float* cmask = (const float*)d_in[1];
  const float* W_iou = (const float*)d_in[2];
  const float* U_iou = (const float*)d_in[3];
  const float* b_iou = (const float*)d_in[4];
  const float* W_f   = (const float*)d_in[5];
  const float* U_f_w = (const float*)d_in[6];
  const float* U_f_b = (const float*)d_in[7];
  const float* b_f   = (const float*)d_in[8];
  const int* cidx    = (const int*)d_in[9];
  const int* ctype   = (const int*)d_in[10];
  float* hout = (float*)d_out;

  unsigned short* BTf = (unsigned short*)d_ws;                // 655360 B
  float* cbuf = (float*)((char*)d_ws + (size_t)(1 << 20));    // 132 MB

  prep_kernel<<<1280, 256, 0, stream>>>(W_iou, U_iou, W_f, U_f_w, BTf);

  // {leaf, lvl1}: 2 trees/block
  fused_kernel<<<2048, 512, 0, stream>>>(emb, cmask, ctype, BTf, b_iou,
                                         U_f_b, b_f, hout, cbuf);
  // {lvl2, lvl3}: 4 trees/block; lvl3 c -> cbuf (read by pair2)
  pair_kernel<4, 3, 48, 56, true><<<1024, 512, 0, stream>>>(
      emb, cmask, cidx, ctype, BTf, b_iou, U_f_b, b_f, hout, cbuf);
  // {lvl4, lvl5}: 16 trees/block; no cbuf writes
  pair_kernel<16, 1, 60, 62, false><<<256, 512, 0, stream>>>(
      emb, cmask, cidx, ctype, BTf, b_iou, U_f_b, b_f, hout, cbuf);
}